// Round 1
// baseline (16630.782 us; speedup 1.0000x reference)
//
#include <hip/hip_runtime.h>
#include <math.h>

#define D_MODEL 512
#define NHEAD   8
#define DHEAD   64
#define SEQ     64
#define BATCH   256
#define NLAYER  8
#define VOCAB   66
#define FFDIM   2048
#define NTOK    (BATCH * SEQ)   // 16384 rows

// ---------------- embedding ----------------
__global__ void embed_kernel(const int* __restrict__ ids, const float* __restrict__ tok,
                             const float* __restrict__ pos, float* __restrict__ x) {
    int idx = blockIdx.x * 256 + threadIdx.x;   // over NTOK*D_MODEL
    int n = idx >> 9;          // row (b*SEQ+s)
    int d = idx & 511;
    int s = n & (SEQ - 1);
    x[idx] = tok[ids[n] * D_MODEL + d] + pos[s * D_MODEL + d];
}

// ---------------- layernorm (unbiased std, eps added to std) ----------------
__global__ void ln_kernel(const float* __restrict__ x, const float* __restrict__ g,
                          const float* __restrict__ b, float* __restrict__ y) {
    int row = blockIdx.x;
    const float* xr = x + (size_t)row * D_MODEL;
    int t = threadIdx.x;  // 256
    float v0 = xr[t], v1 = xr[t + 256];
    float s = v0 + v1, ss = v0 * v0 + v1 * v1;
    #pragma unroll
    for (int o = 32; o >= 1; o >>= 1) {
        s  += __shfl_down(s, o);
        ss += __shfl_down(ss, o);
    }
    __shared__ float ws[4], wss[4];
    int wid = t >> 6, lane = t & 63;
    if (lane == 0) { ws[wid] = s; wss[wid] = ss; }
    __syncthreads();
    if (t == 0) {
        float S = ws[0] + ws[1] + ws[2] + ws[3];
        float SS = wss[0] + wss[1] + wss[2] + wss[3];
        float mean = S / (float)D_MODEL;
        float var = (SS - (float)D_MODEL * mean * mean) / (float)(D_MODEL - 1);
        var = fmaxf(var, 0.f);
        ws[0] = mean;
        wss[0] = sqrtf(var) + 1e-10f;
    }
    __syncthreads();
    float mean = ws[0], denom = wss[0];
    float* yr = y + (size_t)row * D_MODEL;
    yr[t]       = (v0 - mean) / denom * g[t]       + b[t];
    yr[t + 256] = (v1 - mean) / denom * g[t + 256] + b[t + 256];
}

// ---------------- tiled fp32 GEMM: C = act(A@W + bias [+ addsrc]) ----------------
// A [N,K] row-major, W [K,M] row-major, C [N,M]. N,M % 64 == 0, K % 16 == 0.
template <int ACT, bool ADD>
__global__ __launch_bounds__(256) void gemm_kernel(
        const float* __restrict__ A, const float* __restrict__ W,
        const float* __restrict__ bias, const float* __restrict__ addsrc,
        float* __restrict__ C, int K, int M) {
    __shared__ float As[16][65];  // [k][row], padded
    __shared__ float Bs[16][64];  // [k][col]
    int tid = threadIdx.x;
    int tx = tid & 15, ty = tid >> 4;
    int row0 = blockIdx.y * 64;
    int col0 = blockIdx.x * 64;
    float acc[4][4] = {};
    for (int kt = 0; kt < K; kt += 16) {
        #pragma unroll
        for (int i = 0; i < 4; i++) {
            int idx = tid + i * 256;
            int r = idx >> 4, kk = idx & 15;
            As[kk][r] = A[(size_t)(row0 + r) * K + kt + kk];
        }
        #pragma unroll
        for (int i = 0; i < 4; i++) {
            int idx = tid + i * 256;
            int kk = idx >> 6, c = idx & 63;
            Bs[kk][c] = W[(size_t)(kt + kk) * M + col0 + c];
        }
        __syncthreads();
        #pragma unroll
        for (int kk = 0; kk < 16; kk++) {
            float a0[4], b0[4];
            #pragma unroll
            for (int i = 0; i < 4; i++) a0[i] = As[kk][ty + i * 16];
            #pragma unroll
            for (int j = 0; j < 4; j++) b0[j] = Bs[kk][tx + j * 16];
            #pragma unroll
            for (int i = 0; i < 4; i++)
                #pragma unroll
                for (int j = 0; j < 4; j++)
                    acc[i][j] += a0[i] * b0[j];
        }
        __syncthreads();
    }
    #pragma unroll
    for (int i = 0; i < 4; i++) {
        int r = row0 + ty + i * 16;
        #pragma unroll
        for (int j = 0; j < 4; j++) {
            int c = col0 + tx + j * 16;
            float val = acc[i][j];
            if (bias) val += bias[c];
            if (ADD) val += addsrc[(size_t)r * M + c];
            if (ACT == 1) val = 0.5f * val * (1.f + erff(val * 0.70710678118654752f));
            C[(size_t)r * M + c] = val;
        }
    }
}

// ---------------- causal attention, one block per (b,h) ----------------
__global__ __launch_bounds__(256) void attn_kernel(
        const float* __restrict__ Q, const float* __restrict__ K,
        const float* __restrict__ V, float* __restrict__ O) {
    int bh = blockIdx.x;
    int b = bh >> 3, h = bh & 7;
    __shared__ float q[SEQ][DHEAD], k[SEQ][DHEAD], v[SEQ][DHEAD], sc[SEQ][SEQ];
    int t = threadIdx.x;  // 256
    const float scale = 0.04419417382415922f;  // 1/sqrt(d_model=512)
    size_t base = (size_t)(b * SEQ) * D_MODEL + h * DHEAD;
    #pragma unroll
    for (int i = 0; i < 16; i++) {
        int idx = t + i * 256;          // 0..4095
        int r = idx >> 6, c = idx & 63;
        q[r][c] = Q[base + (size_t)r * D_MODEL + c];
        k[r][c] = K[base + (size_t)r * D_MODEL + c];
        v[r][c] = V[base + (size_t)r * D_MODEL + c];
    }
    __syncthreads();
    #pragma unroll
    for (int i = 0; i < 16; i++) {
        int idx = t + i * 256;
        int r = idx >> 6, c = idx & 63;
        float acc;
        if (c <= r) {
            acc = 0.f;
            for (int e = 0; e < DHEAD; e++) acc += q[r][e] * k[c][e];
            acc *= scale;
        } else {
            acc = -INFINITY;
        }
        sc[r][c] = acc;
    }
    __syncthreads();
    if (t < SEQ) {
        int r = t;
        float m = -INFINITY;
        for (int j = 0; j <= r; j++) m = fmaxf(m, sc[r][j]);
        float sum = 0.f;
        for (int j = 0; j <= r; j++) { float e = expf(sc[r][j] - m); sc[r][j] = e; sum += e; }
        float inv = 1.f / sum;
        for (int j = 0; j <= r; j++) sc[r][j] *= inv;
        for (int j = r + 1; j < SEQ; j++) sc[r][j] = 0.f;
    }
    __syncthreads();
    #pragma unroll
    for (int i = 0; i < 16; i++) {
        int idx = t + i * 256;
        int r = idx >> 6, c = idx & 63;
        float acc = 0.f;
        for (int j = 0; j <= r; j++) acc += sc[r][j] * v[j][c];
        O[base + (size_t)r * D_MODEL + c] = acc;
    }
}

// ---------------- logits + log-softmax loss ----------------
__global__ void zero_kernel(float* p) { if (threadIdx.x == 0) *p = 0.f; }

__global__ __launch_bounds__(128) void logits_kernel(
        const float* __restrict__ X, const float* __restrict__ Wu,
        const float* __restrict__ bu, const int* __restrict__ tgt,
        float* __restrict__ out, float* __restrict__ loss) {
    int row = blockIdx.x;
    __shared__ float xs[D_MODEL];
    __shared__ float lg[VOCAB];
    int t = threadIdx.x;  // 128
    for (int i = t; i < D_MODEL; i += 128) xs[i] = X[(size_t)row * D_MODEL + i];
    __syncthreads();
    if (t < VOCAB) {
        float acc = bu[t];
        for (int d = 0; d < D_MODEL; d++) acc += xs[d] * Wu[(size_t)d * VOCAB + t];
        lg[t] = acc;
        out[(size_t)row * VOCAB + t] = acc;
    }
    __syncthreads();
    if (t == 0) {
        float m = -INFINITY;
        for (int j = 0; j < VOCAB; j++) m = fmaxf(m, lg[j]);
        float s = 0.f;
        for (int j = 0; j < VOCAB; j++) s += expf(lg[j] - m);
        float lp = lg[tgt[row]] - m - logf(s);
        atomicAdd(loss, -lp / (float)NTOK);
    }
}

extern "C" void kernel_launch(void* const* d_in, const int* in_sizes, int n_in,
                              void* d_out, int out_size, void* d_ws, size_t ws_size,
                              hipStream_t stream) {
    const int*   input_ids = (const int*)  d_in[0];
    const int*   targets   = (const int*)  d_in[1];
    const float* tok_emb   = (const float*)d_in[2];
    const float* pos_emb   = (const float*)d_in[3];
    const float* Wq        = (const float*)d_in[4];
    const float* Wk        = (const float*)d_in[5];
    const float* Wv        = (const float*)d_in[6];
    const float* Wo        = (const float*)d_in[7];
    const float* bo        = (const float*)d_in[8];
    const float* W1        = (const float*)d_in[9];
    const float* b1        = (const float*)d_in[10];
    const float* W2        = (const float*)d_in[11];
    const float* b2        = (const float*)d_in[12];
    const float* ln1_g     = (const float*)d_in[13];
    const float* ln1_b     = (const float*)d_in[14];
    const float* ln2_g     = (const float*)d_in[15];
    const float* ln2_b     = (const float*)d_in[16];
    const float* lnf_g     = (const float*)d_in[17];
    const float* lnf_b     = (const float*)d_in[18];
    const float* Wu        = (const float*)d_in[19];
    const float* bu        = (const float*)d_in[20];

    float* out  = (float*)d_out;
    float* loss = out + (size_t)NTOK * VOCAB;

    const size_t ND = (size_t)NTOK * D_MODEL;
    float* x   = (float*)d_ws;          // [N,D]
    float* h   = x + ND;                // [N,D]
    float* Qb  = h + ND;                // [N,D]
    float* Kb  = Qb + ND;               // [N,D]
    float* Vb  = Kb + ND;               // [N,D]
    float* ob  = Vb + ND;               // [N,D]
    float* hid = Qb;                    // [N,4D] aliases Q|K|V|o span

    // embedding
    embed_kernel<<<(NTOK * D_MODEL) / 256, 256, 0, stream>>>(input_ids, tok_emb, pos_emb, x);

    dim3 g512(D_MODEL / 64, NTOK / 64);   // M=512
    dim3 gff(FFDIM / 64, NTOK / 64);      // M=2048

    for (int l = 0; l < NLAYER; l++) {
        const float* wq = Wq + (size_t)l * D_MODEL * D_MODEL;
        const float* wk = Wk + (size_t)l * D_MODEL * D_MODEL;
        const float* wv = Wv + (size_t)l * D_MODEL * D_MODEL;
        const float* wo = Wo + (size_t)l * D_MODEL * D_MODEL;
        const float* w1 = W1 + (size_t)l * D_MODEL * FFDIM;
        const float* w2 = W2 + (size_t)l * FFDIM * D_MODEL;

        ln_kernel<<<NTOK, 256, 0, stream>>>(x, ln1_g + l * D_MODEL, ln1_b + l * D_MODEL, h);
        gemm_kernel<0, false><<<g512, 256, 0, stream>>>(h, wq, nullptr, nullptr, Qb, D_MODEL, D_MODEL);
        gemm_kernel<0, false><<<g512, 256, 0, stream>>>(h, wk, nullptr, nullptr, Kb, D_MODEL, D_MODEL);
        gemm_kernel<0, false><<<g512, 256, 0, stream>>>(h, wv, nullptr, nullptr, Vb, D_MODEL, D_MODEL);
        attn_kernel<<<BATCH * NHEAD, 256, 0, stream>>>(Qb, Kb, Vb, ob);
        gemm_kernel<0, true><<<g512, 256, 0, stream>>>(ob, wo, bo + l * D_MODEL, x, x, D_MODEL, D_MODEL);
        ln_kernel<<<NTOK, 256, 0, stream>>>(x, ln2_g + l * D_MODEL, ln2_b + l * D_MODEL, h);
        gemm_kernel<1, false><<<gff, 256, 0, stream>>>(h, w1, b1 + l * FFDIM, nullptr, hid, D_MODEL, FFDIM);
        gemm_kernel<0, true><<<g512, 256, 0, stream>>>(hid, w2, b2 + l * D_MODEL, x, x, FFDIM, D_MODEL);
    }

    ln_kernel<<<NTOK, 256, 0, stream>>>(x, lnf_g, lnf_b, h);
    zero_kernel<<<1, 64, 0, stream>>>(loss);
    logits_kernel<<<NTOK, 128, 0, stream>>>(h, Wu, bu, targets, out, loss);
}

// Round 2
// 4079.322 us; speedup vs baseline: 4.0768x; 4.0768x over previous
//
#include <hip/hip_runtime.h>
#include <hip/hip_bf16.h>
#include <math.h>

#define D_MODEL 512
#define NHEAD   8
#define DHEAD   64
#define SEQ     64
#define BATCH   256
#define NLAYER  8
#define VOCAB   66
#define FFDIM   2048
#define NTOK    (BATCH * SEQ)   // 16384 rows

typedef __attribute__((ext_vector_type(8))) short short8;   // 8 bf16 = 4 VGPRs
typedef __attribute__((ext_vector_type(4))) float f32x4;

__device__ inline void async_copy16(const void* g, void* l) {
    __builtin_amdgcn_global_load_lds(
        (const __attribute__((address_space(1))) void*)g,
        (__attribute__((address_space(3))) void*)l,
        16, 0, 0);
}

// ---------------- weight fp32 [K,M] -> bf16 [M,K] transpose ----------------
__global__ __launch_bounds__(256) void transpose_conv(
        const float* __restrict__ W, __hip_bfloat16* __restrict__ Wt,
        int K, int M, size_t inLS, size_t outLS, int rowOff) {
    __shared__ float tile[32][33];
    int m0 = blockIdx.x * 32, k0 = blockIdx.y * 32;
    const float* Wl = W + blockIdx.z * inLS;
    __hip_bfloat16* Wtl = Wt + blockIdx.z * outLS;
    int t = threadIdx.x;
    #pragma unroll
    for (int p = 0; p < 4; p++) {
        int idx = t + p * 256;
        int kr = idx >> 5, mc = idx & 31;
        tile[kr][mc] = Wl[(size_t)(k0 + kr) * M + m0 + mc];
    }
    __syncthreads();
    #pragma unroll
    for (int p = 0; p < 4; p++) {
        int idx = t + p * 256;
        int mr = idx >> 5, kc = idx & 31;
        Wtl[(size_t)(rowOff + m0 + mr) * K + k0 + kc] = __float2bfloat16(tile[kc][mr]);
    }
}

// ---------------- embedding (fp32 residual) ----------------
__global__ void embed_kernel(const int* __restrict__ ids, const float* __restrict__ tok,
                             const float* __restrict__ pos, float* __restrict__ x) {
    int idx = blockIdx.x * 256 + threadIdx.x;
    int n = idx >> 9;
    int d = idx & 511;
    int s = n & (SEQ - 1);
    x[idx] = tok[ids[n] * D_MODEL + d] + pos[s * D_MODEL + d];
}

// ---------------- layernorm: fp32 in -> bf16 out ----------------
__global__ void ln_kernel(const float* __restrict__ x, const float* __restrict__ g,
                          const float* __restrict__ b, __hip_bfloat16* __restrict__ y) {
    int row = blockIdx.x;
    const float* xr = x + (size_t)row * D_MODEL;
    int t = threadIdx.x;  // 256
    float v0 = xr[t], v1 = xr[t + 256];
    float s = v0 + v1, ss = v0 * v0 + v1 * v1;
    #pragma unroll
    for (int o = 32; o >= 1; o >>= 1) {
        s  += __shfl_down(s, o);
        ss += __shfl_down(ss, o);
    }
    __shared__ float ws[4], wss[4];
    int wid = t >> 6, lane = t & 63;
    if (lane == 0) { ws[wid] = s; wss[wid] = ss; }
    __syncthreads();
    if (t == 0) {
        float S = ws[0] + ws[1] + ws[2] + ws[3];
        float SS = wss[0] + wss[1] + wss[2] + wss[3];
        float mean = S / (float)D_MODEL;
        float var = (SS - (float)D_MODEL * mean * mean) / (float)(D_MODEL - 1);
        var = fmaxf(var, 0.f);
        ws[0] = mean;
        wss[0] = sqrtf(var) + 1e-10f;
    }
    __syncthreads();
    float mean = ws[0], denom = wss[0];
    __hip_bfloat16* yr = y + (size_t)row * D_MODEL;
    yr[t]       = __float2bfloat16((v0 - mean) / denom * g[t]       + b[t]);
    yr[t + 256] = __float2bfloat16((v1 - mean) / denom * g[t + 256] + b[t + 256]);
}

// ---------------- bf16 MFMA GEMM: C = act(A@Bt^T + bias [+ addsrc]) ----------------
// A [N,K] bf16 row-major; Bt [M,K] bf16 row-major (pre-transposed weight).
// Tile 128x128, BK=32, 4 waves in 2x2, 4x4 mfma tiles per wave.
// OUTMODE 0: bf16 store. OUTMODE 1: fp32 store with addsrc residual add.
template <int ACT, int OUTMODE>
__global__ __launch_bounds__(256) void mfma_gemm(
        const __hip_bfloat16* __restrict__ A, const __hip_bfloat16* __restrict__ Bt,
        const float* __restrict__ bias, const float* addsrc,
        void* Cout, int K, int M) {
    __shared__ __align__(16) short As[128 * 32];
    __shared__ __align__(16) short Bs[128 * 32];
    int tid = threadIdx.x;
    int lane = tid & 63, wave = tid >> 6;
    int row0 = blockIdx.y * 128, col0 = blockIdx.x * 128;
    int wr = (wave >> 1) * 64, wc = (wave & 1) * 64;
    int l15 = lane & 15, quad = lane >> 4;

    f32x4 acc[4][4] = {};

    int sr = tid >> 2;            // 0..63 staging row
    int scol = (tid & 3) * 8;     // bf16 offset in 32-wide k-slab
    const short* Ag = (const short*)A + (size_t)(row0 + sr) * K + scol;
    const short* Bg = (const short*)Bt + (size_t)(col0 + sr) * K + scol;
    short* Al = As + sr * 32 + scol;   // byte offset = tid*16 (wave-uniform + lane*16)
    short* Bl = Bs + sr * 32 + scol;

    for (int k0 = 0; k0 < K; k0 += 32) {
        async_copy16(Ag + k0, Al);
        async_copy16(Ag + (size_t)64 * K + k0, Al + 64 * 32);
        async_copy16(Bg + k0, Bl);
        async_copy16(Bg + (size_t)64 * K + k0, Bl + 64 * 32);
        __syncthreads();
        short8 af[4], bf[4];
        #pragma unroll
        for (int i = 0; i < 4; i++)
            af[i] = *(const short8*)(As + (wr + i * 16 + l15) * 32 + quad * 8);
        #pragma unroll
        for (int j = 0; j < 4; j++)
            bf[j] = *(const short8*)(Bs + (wc + j * 16 + l15) * 32 + quad * 8);
        #pragma unroll
        for (int i = 0; i < 4; i++)
            #pragma unroll
            for (int j = 0; j < 4; j++)
                acc[i][j] = __builtin_amdgcn_mfma_f32_16x16x32_bf16(af[i], bf[j], acc[i][j], 0, 0, 0);
        __syncthreads();
    }

    #pragma unroll
    for (int j = 0; j < 4; j++) {
        int col = col0 + wc + j * 16 + l15;
        float bv = bias ? bias[col] : 0.f;
        #pragma unroll
        for (int i = 0; i < 4; i++) {
            int rbase = row0 + wr + i * 16 + quad * 4;
            #pragma unroll
            for (int r = 0; r < 4; r++) {
                int row = rbase + r;
                float v = acc[i][j][r] + bv;
                if (OUTMODE == 1) v += addsrc[(size_t)row * M + col];
                if (ACT == 1) v = 0.5f * v * (1.f + erff(v * 0.70710678118654752f));
                if (OUTMODE == 0)
                    ((__hip_bfloat16*)Cout)[(size_t)row * M + col] = __float2bfloat16(v);
                else
                    ((float*)Cout)[(size_t)row * M + col] = v;
            }
        }
    }
}

// ---------------- causal attention (fp32 math, bf16 in/out) ----------------
// QKV fused [N,1536]: cols 0..511=Q, 512..1023=K, 1024..1535=V; head h at h*64.
__global__ __launch_bounds__(256) void attn_kernel(
        const __hip_bfloat16* __restrict__ QKV, __hip_bfloat16* __restrict__ O) {
    int bh = blockIdx.x;
    int b = bh >> 3, h = bh & 7;
    __shared__ float q[SEQ][DHEAD], k[SEQ][DHEAD], v[SEQ][DHEAD], sc[SEQ][SEQ];
    int t = threadIdx.x;  // 256
    const float scale = 0.04419417382415922f;  // 1/sqrt(512)
    size_t base = (size_t)(b * SEQ) * 1536 + h * DHEAD;
    #pragma unroll
    for (int i = 0; i < 16; i++) {
        int idx = t + i * 256;
        int r = idx >> 6, c = idx & 63;
        size_t rb = base + (size_t)r * 1536 + c;
        q[r][c] = __bfloat162float(QKV[rb]);
        k[r][c] = __bfloat162float(QKV[rb + 512]);
        v[r][c] = __bfloat162float(QKV[rb + 1024]);
    }
    __syncthreads();
    #pragma unroll
    for (int i = 0; i < 16; i++) {
        int idx = t + i * 256;
        int r = idx >> 6, c = idx & 63;
        float acc;
        if (c <= r) {
            acc = 0.f;
            for (int e = 0; e < DHEAD; e++) acc += q[r][e] * k[c][e];
            acc *= scale;
        } else {
            acc = -INFINITY;
        }
        sc[r][c] = acc;
    }
    __syncthreads();
    if (t < SEQ) {
        int r = t;
        float m = -INFINITY;
        for (int j = 0; j <= r; j++) m = fmaxf(m, sc[r][j]);
        float sum = 0.f;
        for (int j = 0; j <= r; j++) { float e = expf(sc[r][j] - m); sc[r][j] = e; sum += e; }
        float inv = 1.f / sum;
        for (int j = 0; j <= r; j++) sc[r][j] *= inv;
        for (int j = r + 1; j < SEQ; j++) sc[r][j] = 0.f;
    }
    __syncthreads();
    #pragma unroll
    for (int i = 0; i < 16; i++) {
        int idx = t + i * 256;
        int r = idx >> 6, c = idx & 63;
        float acc = 0.f;
        for (int j = 0; j <= r; j++) acc += sc[r][j] * v[j][c];
        O[(size_t)(b * SEQ + r) * D_MODEL + h * DHEAD + c] = __float2bfloat16(acc);
    }
}

// ---------------- logits + log-softmax loss ----------------
__global__ void zero_kernel(float* p) { if (threadIdx.x == 0) *p = 0.f; }

__global__ __launch_bounds__(128) void logits_kernel(
        const __hip_bfloat16* __restrict__ X, const float* __restrict__ Wu,
        const float* __restrict__ bu, const int* __restrict__ tgt,
        float* __restrict__ out, float* __restrict__ loss) {
    int row = blockIdx.x;
    __shared__ float xs[D_MODEL];
    __shared__ float lg[VOCAB];
    int t = threadIdx.x;  // 128
    for (int i = t; i < D_MODEL; i += 128) xs[i] = __bfloat162float(X[(size_t)row * D_MODEL + i]);
    __syncthreads();
    if (t < VOCAB) {
        float acc = bu[t];
        for (int d = 0; d < D_MODEL; d++) acc += xs[d] * Wu[(size_t)d * VOCAB + t];
        lg[t] = acc;
        out[(size_t)row * VOCAB + t] = acc;
    }
    __syncthreads();
    if (t == 0) {
        float m = -INFINITY;
        for (int j = 0; j < VOCAB; j++) m = fmaxf(m, lg[j]);
        float s = 0.f;
        for (int j = 0; j < VOCAB; j++) s += expf(lg[j] - m);
        float lp = lg[tgt[row]] - m - logf(s);
        atomicAdd(loss, -lp / (float)NTOK);
    }
}

extern "C" void kernel_launch(void* const* d_in, const int* in_sizes, int n_in,
                              void* d_out, int out_size, void* d_ws, size_t ws_size,
                              hipStream_t stream) {
    const int*   input_ids = (const int*)  d_in[0];
    const int*   targets   = (const int*)  d_in[1];
    const float* tok_emb   = (const float*)d_in[2];
    const float* pos_emb   = (const float*)d_in[3];
    const float* Wq        = (const float*)d_in[4];
    const float* Wk        = (const float*)d_in[5];
    const float* Wv        = (const float*)d_in[6];
    const float* Wo        = (const float*)d_in[7];
    const float* bo        = (const float*)d_in[8];
    const float* W1        = (const float*)d_in[9];
    const float* b1        = (const float*)d_in[10];
    const float* W2        = (const float*)d_in[11];
    const float* b2        = (const float*)d_in[12];
    const float* ln1_g     = (const float*)d_in[13];
    const float* ln1_b     = (const float*)d_in[14];
    const float* ln2_g     = (const float*)d_in[15];
    const float* ln2_b     = (const float*)d_in[16];
    const float* lnf_g     = (const float*)d_in[17];
    const float* lnf_b     = (const float*)d_in[18];
    const float* Wu        = (const float*)d_in[19];
    const float* bu        = (const float*)d_in[20];

    float* out  = (float*)d_out;
    float* loss = out + (size_t)NTOK * VOCAB;

    const size_t ND = (size_t)NTOK * D_MODEL;
    float* x             = (float*)d_ws;                       // [N,D] fp32 residual
    __hip_bfloat16* h    = (__hip_bfloat16*)(x + ND);          // [N,D] bf16 LN out
    __hip_bfloat16* qkv  = h + ND;                             // [N,1536] bf16
    __hip_bfloat16* ob   = qkv + 3 * ND;                       // [N,D] bf16
    __hip_bfloat16* hid  = qkv;                                // [N,4D] bf16, aliases qkv+ob
    __hip_bfloat16* wqkvT = ob + ND;                           // [L][1536][512]
    __hip_bfloat16* woT   = wqkvT + (size_t)NLAYER * 1536 * 512; // [L][512][512]
    __hip_bfloat16* w1T   = woT + (size_t)NLAYER * 512 * 512;    // [L][2048][512]
    __hip_bfloat16* w2T   = w1T + (size_t)NLAYER * 2048 * 512;   // [L][512][2048]

    // ---- weight convert + transpose (every launch; ws is re-poisoned) ----
    transpose_conv<<<dim3(16, 16, NLAYER), 256, 0, stream>>>(Wq, wqkvT, 512, 512,
        (size_t)512 * 512, (size_t)1536 * 512, 0);
    transpose_conv<<<dim3(16, 16, NLAYER), 256, 0, stream>>>(Wk, wqkvT, 512, 512,
        (size_t)512 * 512, (size_t)1536 * 512, 512);
    transpose_conv<<<dim3(16, 16, NLAYER), 256, 0, stream>>>(Wv, wqkvT, 512, 512,
        (size_t)512 * 512, (size_t)1536 * 512, 1024);
    transpose_conv<<<dim3(16, 16, NLAYER), 256, 0, stream>>>(Wo, woT, 512, 512,
        (size_t)512 * 512, (size_t)512 * 512, 0);
    transpose_conv<<<dim3(64, 16, NLAYER), 256, 0, stream>>>(W1, w1T, 512, 2048,
        (size_t)512 * 2048, (size_t)2048 * 512, 0);
    transpose_conv<<<dim3(16, 64, NLAYER), 256, 0, stream>>>(W2, w2T, 2048, 512,
        (size_t)2048 * 512, (size_t)512 * 2048, 0);

    embed_kernel<<<(NTOK * D_MODEL) / 256, 256, 0, stream>>>(input_ids, tok_emb, pos_emb, x);

    for (int l = 0; l < NLAYER; l++) {
        ln_kernel<<<NTOK, 256, 0, stream>>>(x, ln1_g + l * D_MODEL, ln1_b + l * D_MODEL, h);
        mfma_gemm<0, 0><<<dim3(12, 128), 256, 0, stream>>>(
            h, wqkvT + (size_t)l * 1536 * 512, nullptr, nullptr, qkv, 512, 1536);
        attn_kernel<<<BATCH * NHEAD, 256, 0, stream>>>(qkv, ob);
        mfma_gemm<0, 1><<<dim3(4, 128), 256, 0, stream>>>(
            ob, woT + (size_t)l * 512 * 512, bo + l * D_MODEL, x, x, 512, 512);
        ln_kernel<<<NTOK, 256, 0, stream>>>(x, ln2_g + l * D_MODEL, ln2_b + l * D_MODEL, h);
        mfma_gemm<1, 0><<<dim3(16, 128), 256, 0, stream>>>(
            h, w1T + (size_t)l * 2048 * 512, b1 + l * FFDIM, nullptr, hid, 512, 2048);
        mfma_gemm<0, 1><<<dim3(4, 128), 256, 0, stream>>>(
            hid, w2T + (size_t)l * 2048 * 512, b2 + l * D_MODEL, x, x, 2048, 512);
    }

    ln_kernel<<<NTOK, 256, 0, stream>>>(x, lnf_g, lnf_b, h);
    zero_kernel<<<1, 64, 0, stream>>>(loss);
    logits_kernel<<<NTOK, 128, 0, stream>>>(h, Wu, bu, targets, out, loss);
}

// Round 3
// 2508.444 us; speedup vs baseline: 6.6299x; 1.6262x over previous
//
#include <hip/hip_runtime.h>
#include <hip/hip_bf16.h>
#include <math.h>

#define D_MODEL 512
#define NHEAD   8
#define DHEAD   64
#define SEQ     64
#define BATCH   256
#define NLAYER  8
#define VOCAB   66
#define FFDIM   2048
#define NTOK    (BATCH * SEQ)   // 16384 rows

typedef __attribute__((ext_vector_type(8))) short short8;   // 8 bf16 = 4 VGPRs
typedef __attribute__((ext_vector_type(4))) float f32x4;

__device__ inline void async_copy16(const void* g, void* l) {
    __builtin_amdgcn_global_load_lds(
        (const __attribute__((address_space(1))) void*)g,
        (__attribute__((address_space(3))) void*)l,
        16, 0, 0);
}

// ---------------- weight fp32 [K,M] -> bf16 [M,K] transpose ----------------
__global__ __launch_bounds__(256) void transpose_conv(
        const float* __restrict__ W, __hip_bfloat16* __restrict__ Wt,
        int K, int M, size_t inLS, size_t outLS, int rowOff) {
    __shared__ float tile[32][33];
    int m0 = blockIdx.x * 32, k0 = blockIdx.y * 32;
    const float* Wl = W + blockIdx.z * inLS;
    __hip_bfloat16* Wtl = Wt + blockIdx.z * outLS;
    int t = threadIdx.x;
    #pragma unroll
    for (int p = 0; p < 4; p++) {
        int idx = t + p * 256;
        int kr = idx >> 5, mc = idx & 31;
        tile[kr][mc] = Wl[(size_t)(k0 + kr) * M + m0 + mc];
    }
    __syncthreads();
    #pragma unroll
    for (int p = 0; p < 4; p++) {
        int idx = t + p * 256;
        int mr = idx >> 5, kc = idx & 31;
        Wtl[(size_t)(rowOff + m0 + mr) * K + k0 + kc] = __float2bfloat16(tile[kc][mr]);
    }
}

// ---------------- Wu fp32 [512,66] -> bf16 [128,512] transposed, zero-padded ----
__global__ __launch_bounds__(256) void conv_wu(
        const float* __restrict__ Wu, __hip_bfloat16* __restrict__ WuT) {
    int idx = blockIdx.x * 256 + threadIdx.x;   // over 128*512
    int m = idx >> 9, k = idx & 511;
    WuT[idx] = __float2bfloat16(m < VOCAB ? Wu[(size_t)k * VOCAB + m] : 0.f);
}

// ---------------- embedding (fp32 residual) ----------------
__global__ void embed_kernel(const int* __restrict__ ids, const float* __restrict__ tok,
                             const float* __restrict__ pos, float* __restrict__ x) {
    int idx = blockIdx.x * 256 + threadIdx.x;
    int n = idx >> 9;
    int d = idx & 511;
    int s = n & (SEQ - 1);
    x[idx] = tok[ids[n] * D_MODEL + d] + pos[s * D_MODEL + d];
}

// ---------------- layernorm: fp32 in -> bf16 out ----------------
__global__ void ln_kernel(const float* __restrict__ x, const float* __restrict__ g,
                          const float* __restrict__ b, __hip_bfloat16* __restrict__ y) {
    int row = blockIdx.x;
    const float* xr = x + (size_t)row * D_MODEL;
    int t = threadIdx.x;  // 256
    float v0 = xr[t], v1 = xr[t + 256];
    float s = v0 + v1, ss = v0 * v0 + v1 * v1;
    #pragma unroll
    for (int o = 32; o >= 1; o >>= 1) {
        s  += __shfl_down(s, o);
        ss += __shfl_down(ss, o);
    }
    __shared__ float ws[4], wss[4];
    int wid = t >> 6, lane = t & 63;
    if (lane == 0) { ws[wid] = s; wss[wid] = ss; }
    __syncthreads();
    if (t == 0) {
        float S = ws[0] + ws[1] + ws[2] + ws[3];
        float SS = wss[0] + wss[1] + wss[2] + wss[3];
        float mean = S / (float)D_MODEL;
        float var = (SS - (float)D_MODEL * mean * mean) / (float)(D_MODEL - 1);
        var = fmaxf(var, 0.f);
        ws[0] = mean;
        wss[0] = sqrtf(var) + 1e-10f;
    }
    __syncthreads();
    float mean = ws[0], denom = wss[0];
    __hip_bfloat16* yr = y + (size_t)row * D_MODEL;
    yr[t]       = __float2bfloat16((v0 - mean) / denom * g[t]       + b[t]);
    yr[t + 256] = __float2bfloat16((v1 - mean) / denom * g[t + 256] + b[t + 256]);
}

// ---------------- bf16 MFMA GEMM ----------------
// A [N,K] bf16 row-major; Bt [M,K] bf16 row-major (pre-transposed weight).
// Tile 128x128, BK=32. OUTMODE 0: bf16 store. 1: fp32 store + addsrc residual.
// 2: fp32 store, ldc row stride, col < mstore guard (logits).
template <int ACT, int OUTMODE>
__global__ __launch_bounds__(256) void mfma_gemm(
        const __hip_bfloat16* __restrict__ A, const __hip_bfloat16* __restrict__ Bt,
        const float* __restrict__ bias, const float* addsrc,
        void* Cout, int K, int M, int ldc, int mstore) {
    __shared__ __align__(16) short As[128 * 32];
    __shared__ __align__(16) short Bs[128 * 32];
    int tid = threadIdx.x;
    int lane = tid & 63, wave = tid >> 6;
    int row0 = blockIdx.y * 128, col0 = blockIdx.x * 128;
    int wr = (wave >> 1) * 64, wc = (wave & 1) * 64;
    int l15 = lane & 15, quad = lane >> 4;

    f32x4 acc[4][4] = {};

    int sr = tid >> 2;
    int scol = (tid & 3) * 8;
    const short* Ag = (const short*)A + (size_t)(row0 + sr) * K + scol;
    const short* Bg = (const short*)Bt + (size_t)(col0 + sr) * K + scol;
    short* Al = As + sr * 32 + scol;
    short* Bl = Bs + sr * 32 + scol;

    for (int k0 = 0; k0 < K; k0 += 32) {
        async_copy16(Ag + k0, Al);
        async_copy16(Ag + (size_t)64 * K + k0, Al + 64 * 32);
        async_copy16(Bg + k0, Bl);
        async_copy16(Bg + (size_t)64 * K + k0, Bl + 64 * 32);
        __syncthreads();
        short8 af[4], bf[4];
        #pragma unroll
        for (int i = 0; i < 4; i++)
            af[i] = *(const short8*)(As + (wr + i * 16 + l15) * 32 + quad * 8);
        #pragma unroll
        for (int j = 0; j < 4; j++)
            bf[j] = *(const short8*)(Bs + (wc + j * 16 + l15) * 32 + quad * 8);
        #pragma unroll
        for (int i = 0; i < 4; i++)
            #pragma unroll
            for (int j = 0; j < 4; j++)
                acc[i][j] = __builtin_amdgcn_mfma_f32_16x16x32_bf16(af[i], bf[j], acc[i][j], 0, 0, 0);
        __syncthreads();
    }

    #pragma unroll
    for (int j = 0; j < 4; j++) {
        int col = col0 + wc + j * 16 + l15;
        if (OUTMODE == 2 && col >= mstore) continue;
        float bv = bias ? bias[col] : 0.f;
        #pragma unroll
        for (int i = 0; i < 4; i++) {
            int rbase = row0 + wr + i * 16 + quad * 4;
            #pragma unroll
            for (int r = 0; r < 4; r++) {
                int row = rbase + r;
                float v = acc[i][j][r] + bv;
                if (OUTMODE == 1) v += addsrc[(size_t)row * M + col];
                if (ACT == 1) v = 0.5f * v * (1.f + erff(v * 0.70710678118654752f));
                if (OUTMODE == 0)
                    ((__hip_bfloat16*)Cout)[(size_t)row * M + col] = __float2bfloat16(v);
                else
                    ((float*)Cout)[(size_t)row * ldc + col] = v;
            }
        }
    }
}

// ---------------- MFMA causal attention: one block per (b,h) ----------------
// QKV fused [N,1536]; wave w handles score rows 16w..16w+15.
#define PSTRIDE 72
__global__ __launch_bounds__(256) void attn_mfma(
        const __hip_bfloat16* __restrict__ QKV, __hip_bfloat16* __restrict__ O) {
    __shared__ __align__(16) short Vt[64 * PSTRIDE];   // Vt[c][j] = V[j][c]
    __shared__ __align__(16) short P[64 * PSTRIDE];    // P[r][j]
    int bh = blockIdx.x;
    int b = bh >> 3, h = bh & 7;
    int t = threadIdx.x;
    int lane = t & 63, wave = t >> 6;
    int l15 = lane & 15, quad = lane >> 4;
    const float scale = 0.04419417382415922f;  // 1/sqrt(512)
    const short* base = (const short*)QKV + (size_t)(b * SEQ) * 1536 + h * DHEAD;

    // ---- cooperative V transpose into LDS (pairs of rows -> b32 writes) ----
    {
        int j0 = (t >> 3) * 2;          // 0..62 even
        int c0 = (t & 7) * 8;           // 0..56
        const short* vrow = base + 1024 + (size_t)j0 * 1536 + c0;
        short8 va = *(const short8*)vrow;
        short8 vb = *(const short8*)(vrow + 1536);
        #pragma unroll
        for (int s = 0; s < 8; s++) {
            unsigned int packed = ((unsigned int)(unsigned short)vb[s] << 16) |
                                  (unsigned int)(unsigned short)va[s];
            *(unsigned int*)&Vt[(c0 + s) * PSTRIDE + j0] = packed;
        }
    }

    // ---- QK^T for this wave's 16 rows (r0..r0+15), direct global frags ----
    int r0 = wave * 16;
    short8 aq[2], bk[4][2];
    #pragma unroll
    for (int k = 0; k < 2; k++)
        aq[k] = *(const short8*)(base + (size_t)(r0 + l15) * 1536 + quad * 8 + 32 * k);
    #pragma unroll
    for (int j = 0; j < 4; j++)
        #pragma unroll
        for (int k = 0; k < 2; k++)
            bk[j][k] = *(const short8*)(base + 512 + (size_t)(j * 16 + l15) * 1536 + quad * 8 + 32 * k);

    f32x4 sc[4];
    #pragma unroll
    for (int j = 0; j < 4; j++) {
        f32x4 z = {};
        z = __builtin_amdgcn_mfma_f32_16x16x32_bf16(aq[0], bk[j][0], z, 0, 0, 0);
        sc[j] = __builtin_amdgcn_mfma_f32_16x16x32_bf16(aq[1], bk[j][1], z, 0, 0, 0);
    }

    // ---- softmax per row (row = r0 + quad*4 + reg, lives in one 16-lane group) ----
    float p[4][4];
    #pragma unroll
    for (int reg = 0; reg < 4; reg++) {
        int r = r0 + quad * 4 + reg;
        float m = -INFINITY;
        #pragma unroll
        for (int j = 0; j < 4; j++) {
            int c = j * 16 + l15;
            float s = (c <= r) ? sc[j][reg] * scale : -INFINITY;
            p[j][reg] = s;
            m = fmaxf(m, s);
        }
        #pragma unroll
        for (int o = 1; o < 16; o <<= 1) m = fmaxf(m, __shfl_xor(m, o));
        float sum = 0.f;
        #pragma unroll
        for (int j = 0; j < 4; j++) {
            float e = (p[j][reg] == -INFINITY) ? 0.f : expf(p[j][reg] - m);
            p[j][reg] = e;
            sum += e;
        }
        #pragma unroll
        for (int o = 1; o < 16; o <<= 1) sum += __shfl_xor(sum, o);
        float inv = 1.f / sum;
        #pragma unroll
        for (int j = 0; j < 4; j++) p[j][reg] *= inv;
    }

    // ---- write P (bf16) to LDS rows r0..r0+15 ----
    #pragma unroll
    for (int j = 0; j < 4; j++)
        #pragma unroll
        for (int reg = 0; reg < 4; reg++) {
            int r = r0 + quad * 4 + reg;
            P[r * PSTRIDE + j * 16 + l15] =
                ((__hip_bfloat16_raw)__float2bfloat16(p[j][reg])).x;
        }

    __syncthreads();   // Vt complete + P visible

    // ---- PV: O rows r0..r0+15 ----
    short8 ap[2];
    #pragma unroll
    for (int k = 0; k < 2; k++)
        ap[k] = *(const short8*)(P + (r0 + l15) * PSTRIDE + quad * 8 + 32 * k);
    #pragma unroll
    for (int jt = 0; jt < 4; jt++) {
        short8 bv0 = *(const short8*)(Vt + (jt * 16 + l15) * PSTRIDE + quad * 8);
        short8 bv1 = *(const short8*)(Vt + (jt * 16 + l15) * PSTRIDE + quad * 8 + 32);
        f32x4 o = {};
        o = __builtin_amdgcn_mfma_f32_16x16x32_bf16(ap[0], bv0, o, 0, 0, 0);
        o = __builtin_amdgcn_mfma_f32_16x16x32_bf16(ap[1], bv1, o, 0, 0, 0);
        #pragma unroll
        for (int reg = 0; reg < 4; reg++) {
            int r = r0 + quad * 4 + reg;
            int c = jt * 16 + l15;
            O[(size_t)(b * SEQ + r) * D_MODEL + h * DHEAD + c] = __float2bfloat16(o[reg]);
        }
    }
}

// ---------------- loss: wave per row over fp32 logits ----------------
__global__ void zero_kernel(float* p) { if (threadIdx.x == 0) *p = 0.f; }

__global__ __launch_bounds__(256) void loss_kernel(
        const float* __restrict__ lg, const int* __restrict__ tgt,
        float* __restrict__ loss) {
    int row = blockIdx.x * 4 + (threadIdx.x >> 6);
    int l = threadIdx.x & 63;
    const float* lr = lg + (size_t)row * VOCAB;
    float a = lr[l];
    float bx = (l < VOCAB - 64) ? lr[64 + l] : -INFINITY;
    float m = fmaxf(a, bx);
    #pragma unroll
    for (int o = 32; o >= 1; o >>= 1) m = fmaxf(m, __shfl_xor(m, o));
    float s = expf(a - m) + ((l < VOCAB - 64) ? expf(bx - m) : 0.f);
    #pragma unroll
    for (int o = 32; o >= 1; o >>= 1) s += __shfl_xor(s, o);
    if (l == 0) {
        float lp = lr[tgt[row]] - m - logf(s);
        atomicAdd(loss, -lp / (float)NTOK);
    }
}

extern "C" void kernel_launch(void* const* d_in, const int* in_sizes, int n_in,
                              void* d_out, int out_size, void* d_ws, size_t ws_size,
                              hipStream_t stream) {
    const int*   input_ids = (const int*)  d_in[0];
    const int*   targets   = (const int*)  d_in[1];
    const float* tok_emb   = (const float*)d_in[2];
    const float* pos_emb   = (const float*)d_in[3];
    const float* Wq        = (const float*)d_in[4];
    const float* Wk        = (const float*)d_in[5];
    const float* Wv        = (const float*)d_in[6];
    const float* Wo        = (const float*)d_in[7];
    const float* bo        = (const float*)d_in[8];
    const float* W1        = (const float*)d_in[9];
    const float* b1        = (const float*)d_in[10];
    const float* W2        = (const float*)d_in[11];
    const float* b2        = (const float*)d_in[12];
    const float* ln1_g     = (const float*)d_in[13];
    const float* ln1_b     = (const float*)d_in[14];
    const float* ln2_g     = (const float*)d_in[15];
    const float* ln2_b     = (const float*)d_in[16];
    const float* lnf_g     = (const float*)d_in[17];
    const float* lnf_b     = (const float*)d_in[18];
    const float* Wu        = (const float*)d_in[19];
    const float* bu        = (const float*)d_in[20];

    float* out  = (float*)d_out;
    float* loss = out + (size_t)NTOK * VOCAB;

    const size_t ND = (size_t)NTOK * D_MODEL;
    float* x             = (float*)d_ws;                         // [N,D] fp32 residual
    __hip_bfloat16* h    = (__hip_bfloat16*)(x + ND);            // [N,D] bf16 LN out
    __hip_bfloat16* qkv  = h + ND;                               // [N,1536] bf16
    __hip_bfloat16* ob   = qkv + 3 * ND;                         // [N,D] bf16
    __hip_bfloat16* hid  = qkv;                                  // [N,4D] bf16 (aliases)
    __hip_bfloat16* wqkvT = ob + ND;                             // [L][1536][512]
    __hip_bfloat16* woT   = wqkvT + (size_t)NLAYER * 1536 * 512; // [L][512][512]
    __hip_bfloat16* w1T   = woT + (size_t)NLAYER * 512 * 512;    // [L][2048][512]
    __hip_bfloat16* w2T   = w1T + (size_t)NLAYER * 2048 * 512;   // [L][512][2048]
    __hip_bfloat16* wuT   = w2T + (size_t)NLAYER * 2048 * 512;   // [128][512]

    // ---- weight convert + transpose ----
    transpose_conv<<<dim3(16, 16, NLAYER), 256, 0, stream>>>(Wq, wqkvT, 512, 512,
        (size_t)512 * 512, (size_t)1536 * 512, 0);
    transpose_conv<<<dim3(16, 16, NLAYER), 256, 0, stream>>>(Wk, wqkvT, 512, 512,
        (size_t)512 * 512, (size_t)1536 * 512, 512);
    transpose_conv<<<dim3(16, 16, NLAYER), 256, 0, stream>>>(Wv, wqkvT, 512, 512,
        (size_t)512 * 512, (size_t)1536 * 512, 1024);
    transpose_conv<<<dim3(16, 16, NLAYER), 256, 0, stream>>>(Wo, woT, 512, 512,
        (size_t)512 * 512, (size_t)512 * 512, 0);
    transpose_conv<<<dim3(64, 16, NLAYER), 256, 0, stream>>>(W1, w1T, 512, 2048,
        (size_t)512 * 2048, (size_t)2048 * 512, 0);
    transpose_conv<<<dim3(16, 64, NLAYER), 256, 0, stream>>>(W2, w2T, 2048, 512,
        (size_t)2048 * 512, (size_t)512 * 2048, 0);
    conv_wu<<<(128 * 512) / 256, 256, 0, stream>>>(Wu, wuT);

    embed_kernel<<<(NTOK * D_MODEL) / 256, 256, 0, stream>>>(input_ids, tok_emb, pos_emb, x);

    for (int l = 0; l < NLAYER; l++) {
        ln_kernel<<<NTOK, 256, 0, stream>>>(x, ln1_g + l * D_MODEL, ln1_b + l * D_MODEL, h);
        mfma_gemm<0, 0><<<dim3(12, 128), 256, 0, stream>>>(
            h, wqkvT + (size_t)l * 1536 * 512, nullptr, nullptr, qkv, 512, 1536, 1536, 1536);
        attn_mfma<<<BATCH * NHEAD, 256, 0, stream>>>(qkv, ob);
        mfma_gemm<0, 1><<<dim3(4, 128), 256, 0, stream>>>(
            ob, woT + (size_t)l * 512 * 512, bo + l * D_MODEL, x, x, 512, 512, 512, 512);
        ln_kernel<<<NTOK, 256, 0, stream>>>(x, ln2_g + l * D_MODEL, ln2_b + l * D_MODEL, h);
        mfma_gemm<1, 0><<<dim3(16, 128), 256, 0, stream>>>(
            h, w1T + (size_t)l * 2048 * 512, b1 + l * FFDIM, nullptr, hid, 512, 2048, 2048, 2048);
        mfma_gemm<0, 1><<<dim3(4, 128), 256, 0, stream>>>(
            hid, w2T + (size_t)l * 2048 * 512, b2 + l * D_MODEL, x, x, 2048, 512, 512, 512);
    }

    ln_kernel<<<NTOK, 256, 0, stream>>>(x, lnf_g, lnf_b, h);
    mfma_gemm<0, 2><<<dim3(1, 128), 256, 0, stream>>>(
        h, wuT, bu, nullptr, out, 512, 128, VOCAB, VOCAB);
    zero_kernel<<<1, 64, 0, stream>>>(loss);
    loss_kernel<<<NTOK / 4, 256, 0, stream>>>(out, targets, loss);
}

// Round 4
// 2395.469 us; speedup vs baseline: 6.9426x; 1.0472x over previous
//
#include <hip/hip_runtime.h>
#include <hip/hip_bf16.h>
#include <math.h>

#define D_MODEL 512
#define NHEAD   8
#define DHEAD   64
#define SEQ     64
#define BATCH   256
#define NLAYER  8
#define VOCAB   66
#define FFDIM   2048
#define NTOK    (BATCH * SEQ)   // 16384 rows

typedef __attribute__((ext_vector_type(8))) short short8;    // 8 bf16 = 4 VGPRs
typedef __attribute__((ext_vector_type(4))) float f32x4;
typedef __attribute__((ext_vector_type(16))) float f32x16;

__device__ inline void async_copy16(const void* g, void* l) {
    __builtin_amdgcn_global_load_lds(
        (const __attribute__((address_space(1))) void*)g,
        (__attribute__((address_space(3))) void*)l,
        16, 0, 0);
}

// ---------------- weight fp32 [K,M] -> bf16 [M,K] transpose ----------------
__global__ __launch_bounds__(256) void transpose_conv(
        const float* __restrict__ W, __hip_bfloat16* __restrict__ Wt,
        int K, int M, size_t inLS, size_t outLS, int rowOff) {
    __shared__ float tile[32][33];
    int m0 = blockIdx.x * 32, k0 = blockIdx.y * 32;
    const float* Wl = W + blockIdx.z * inLS;
    __hip_bfloat16* Wtl = Wt + blockIdx.z * outLS;
    int t = threadIdx.x;
    #pragma unroll
    for (int p = 0; p < 4; p++) {
        int idx = t + p * 256;
        int kr = idx >> 5, mc = idx & 31;
        tile[kr][mc] = Wl[(size_t)(k0 + kr) * M + m0 + mc];
    }
    __syncthreads();
    #pragma unroll
    for (int p = 0; p < 4; p++) {
        int idx = t + p * 256;
        int mr = idx >> 5, kc = idx & 31;
        Wtl[(size_t)(rowOff + m0 + mr) * K + k0 + kc] = __float2bfloat16(tile[kc][mr]);
    }
}

// ---------------- Wu fp32 [512,66] -> bf16 [128,512] transposed, zero-padded ----
__global__ __launch_bounds__(256) void conv_wu(
        const float* __restrict__ Wu, __hip_bfloat16* __restrict__ WuT) {
    int idx = blockIdx.x * 256 + threadIdx.x;   // over 128*512
    int m = idx >> 9, k = idx & 511;
    WuT[idx] = __float2bfloat16(m < VOCAB ? Wu[(size_t)k * VOCAB + m] : 0.f);
}

// ---------------- embedding (fp32 residual) ----------------
__global__ void embed_kernel(const int* __restrict__ ids, const float* __restrict__ tok,
                             const float* __restrict__ pos, float* __restrict__ x) {
    int idx = blockIdx.x * 256 + threadIdx.x;
    int n = idx >> 9;
    int d = idx & 511;
    int s = n & (SEQ - 1);
    x[idx] = tok[ids[n] * D_MODEL + d] + pos[s * D_MODEL + d];
}

// ---------------- layernorm: wave per row, no barriers ----------------
__global__ __launch_bounds__(256) void ln_kernel(
        const float* __restrict__ x, const float* __restrict__ g,
        const float* __restrict__ b, __hip_bfloat16* __restrict__ y) {
    int row = blockIdx.x * 4 + (threadIdx.x >> 6);
    int lane = threadIdx.x & 63;
    const float* xr = x + (size_t)row * D_MODEL + lane * 8;
    f32x4 v0 = *(const f32x4*)xr;
    f32x4 v1 = *(const f32x4*)(xr + 4);
    float s = 0.f, ss = 0.f;
    #pragma unroll
    for (int e = 0; e < 4; e++) { s += v0[e] + v1[e]; ss += v0[e] * v0[e] + v1[e] * v1[e]; }
    #pragma unroll
    for (int o = 1; o < 64; o <<= 1) {
        s  += __shfl_xor(s, o);
        ss += __shfl_xor(ss, o);
    }
    float mean = s / (float)D_MODEL;
    float var = (ss - (float)D_MODEL * mean * mean) / (float)(D_MODEL - 1);
    float denom = sqrtf(fmaxf(var, 0.f)) + 1e-10f;
    f32x4 g0 = *(const f32x4*)(g + lane * 8);
    f32x4 g1 = *(const f32x4*)(g + lane * 8 + 4);
    f32x4 b0 = *(const f32x4*)(b + lane * 8);
    f32x4 b1 = *(const f32x4*)(b + lane * 8 + 4);
    short8 outv;
    #pragma unroll
    for (int e = 0; e < 4; e++) {
        outv[e]     = ((__hip_bfloat16_raw)__float2bfloat16((v0[e] - mean) / denom * g0[e] + b0[e])).x;
        outv[e + 4] = ((__hip_bfloat16_raw)__float2bfloat16((v1[e] - mean) / denom * g1[e] + b1[e])).x;
    }
    *(short8*)((short*)y + (size_t)row * D_MODEL + lane * 8) = outv;
}

// ---------------- bf16 MFMA GEMM (32x32x16) ----------------
// A [N,K] bf16 row-major; Bt [M,K] bf16 row-major (pre-transposed weight).
// Tile 128x128, BK=32, 4 waves 2x2, each wave 64x64 = 2x2 of 32x32 tiles.
// OUTMODE 0: bf16 store. 1: fp32 store + addsrc residual.
// 2: fp32 store, ldc row stride, col < mstore guard (logits).
template <int ACT, int OUTMODE>
__global__ __launch_bounds__(256) void mfma_gemm(
        const __hip_bfloat16* __restrict__ A, const __hip_bfloat16* __restrict__ Bt,
        const float* __restrict__ bias, const float* addsrc,
        void* Cout, int K, int M, int ldc, int mstore) {
    __shared__ __align__(16) short As[128 * 32];
    __shared__ __align__(16) short Bs[128 * 32];
    int tid = threadIdx.x;
    int lane = tid & 63, wave = tid >> 6;
    int row0 = blockIdx.y * 128, col0 = blockIdx.x * 128;
    int wr = (wave >> 1) * 64, wc = (wave & 1) * 64;
    int l31 = lane & 31, h32 = lane >> 5;

    f32x16 acc[2][2] = {};

    int sr = tid >> 2;
    int scol = (tid & 3) * 8;
    const short* Ag = (const short*)A + (size_t)(row0 + sr) * K + scol;
    const short* Bg = (const short*)Bt + (size_t)(col0 + sr) * K + scol;
    short* Al = As + sr * 32 + scol;
    short* Bl = Bs + sr * 32 + scol;

    for (int k0 = 0; k0 < K; k0 += 32) {
        async_copy16(Ag + k0, Al);
        async_copy16(Ag + (size_t)64 * K + k0, Al + 64 * 32);
        async_copy16(Bg + k0, Bl);
        async_copy16(Bg + (size_t)64 * K + k0, Bl + 64 * 32);
        __syncthreads();
        short8 af[2][2], bf[2][2];
        #pragma unroll
        for (int i = 0; i < 2; i++)
            #pragma unroll
            for (int kh = 0; kh < 2; kh++) {
                af[i][kh] = *(const short8*)(As + (wr + i * 32 + l31) * 32 + kh * 16 + h32 * 8);
                bf[i][kh] = *(const short8*)(Bs + (wc + i * 32 + l31) * 32 + kh * 16 + h32 * 8);
            }
        #pragma unroll
        for (int i = 0; i < 2; i++)
            #pragma unroll
            for (int j = 0; j < 2; j++) {
                acc[i][j] = __builtin_amdgcn_mfma_f32_32x32x16_bf16(af[i][0], bf[j][0], acc[i][j], 0, 0, 0);
                acc[i][j] = __builtin_amdgcn_mfma_f32_32x32x16_bf16(af[i][1], bf[j][1], acc[i][j], 0, 0, 0);
            }
        __syncthreads();
    }

    // C/D layout: col = lane&31, row = (reg&3) + 8*(reg>>2) + 4*(lane>>5)
    #pragma unroll
    for (int j = 0; j < 2; j++) {
        int col = col0 + wc + j * 32 + l31;
        if (OUTMODE == 2 && col >= mstore) continue;
        float bv = bias ? bias[col] : 0.f;
        #pragma unroll
        for (int i = 0; i < 2; i++) {
            int rbase = row0 + wr + i * 32 + 4 * h32;
            #pragma unroll
            for (int r = 0; r < 16; r++) {
                int row = rbase + (r & 3) + 8 * (r >> 2);
                float v = acc[i][j][r] + bv;
                if (OUTMODE == 1) v += addsrc[(size_t)row * M + col];
                if (ACT == 1) v = 0.5f * v * (1.f + erff(v * 0.70710678118654752f));
                if (OUTMODE == 0)
                    ((__hip_bfloat16*)Cout)[(size_t)row * M + col] = __float2bfloat16(v);
                else
                    ((float*)Cout)[(size_t)row * ldc + col] = v;
            }
        }
    }
}

// ---------------- MFMA causal attention: one block per (b,h) ----------------
#define PSTRIDE 72
__global__ __launch_bounds__(256) void attn_mfma(
        const __hip_bfloat16* __restrict__ QKV, __hip_bfloat16* __restrict__ O) {
    __shared__ __align__(16) short Vt[64 * PSTRIDE];   // Vt[c][j] = V[j][c]
    __shared__ __align__(16) short P[64 * PSTRIDE];    // P[r][j]
    int bh = blockIdx.x;
    int b = bh >> 3, h = bh & 7;
    int t = threadIdx.x;
    int lane = t & 63, wave = t >> 6;
    int l15 = lane & 15, quad = lane >> 4;
    const float scale = 0.04419417382415922f;  // 1/sqrt(512)
    const short* base = (const short*)QKV + (size_t)(b * SEQ) * 1536 + h * DHEAD;

    // cooperative V transpose into LDS
    {
        int j0 = (t >> 3) * 2;
        int c0 = (t & 7) * 8;
        const short* vrow = base + 1024 + (size_t)j0 * 1536 + c0;
        short8 va = *(const short8*)vrow;
        short8 vb = *(const short8*)(vrow + 1536);
        #pragma unroll
        for (int s = 0; s < 8; s++) {
            unsigned int packed = ((unsigned int)(unsigned short)vb[s] << 16) |
                                  (unsigned int)(unsigned short)va[s];
            *(unsigned int*)&Vt[(c0 + s) * PSTRIDE + j0] = packed;
        }
    }

    // QK^T for this wave's 16 rows
    int r0 = wave * 16;
    short8 aq[2], bk[4][2];
    #pragma unroll
    for (int k = 0; k < 2; k++)
        aq[k] = *(const short8*)(base + (size_t)(r0 + l15) * 1536 + quad * 8 + 32 * k);
    #pragma unroll
    for (int j = 0; j < 4; j++)
        #pragma unroll
        for (int k = 0; k < 2; k++)
            bk[j][k] = *(const short8*)(base + 512 + (size_t)(j * 16 + l15) * 1536 + quad * 8 + 32 * k);

    f32x4 sc[4];
    #pragma unroll
    for (int j = 0; j < 4; j++) {
        f32x4 z = {};
        z = __builtin_amdgcn_mfma_f32_16x16x32_bf16(aq[0], bk[j][0], z, 0, 0, 0);
        sc[j] = __builtin_amdgcn_mfma_f32_16x16x32_bf16(aq[1], bk[j][1], z, 0, 0, 0);
    }

    // softmax per row
    float p[4][4];
    #pragma unroll
    for (int reg = 0; reg < 4; reg++) {
        int r = r0 + quad * 4 + reg;
        float m = -INFINITY;
        #pragma unroll
        for (int j = 0; j < 4; j++) {
            int c = j * 16 + l15;
            float s = (c <= r) ? sc[j][reg] * scale : -INFINITY;
            p[j][reg] = s;
            m = fmaxf(m, s);
        }
        #pragma unroll
        for (int o = 1; o < 16; o <<= 1) m = fmaxf(m, __shfl_xor(m, o));
        float sum = 0.f;
        #pragma unroll
        for (int j = 0; j < 4; j++) {
            float e = (p[j][reg] == -INFINITY) ? 0.f : expf(p[j][reg] - m);
            p[j][reg] = e;
            sum += e;
        }
        #pragma unroll
        for (int o = 1; o < 16; o <<= 1) sum += __shfl_xor(sum, o);
        float inv = 1.f / sum;
        #pragma unroll
        for (int j = 0; j < 4; j++) p[j][reg] *= inv;
    }

    // write P (bf16) to LDS
    #pragma unroll
    for (int j = 0; j < 4; j++)
        #pragma unroll
        for (int reg = 0; reg < 4; reg++) {
            int r = r0 + quad * 4 + reg;
            P[r * PSTRIDE + j * 16 + l15] =
                ((__hip_bfloat16_raw)__float2bfloat16(p[j][reg])).x;
        }

    __syncthreads();

    // PV
    short8 ap[2];
    #pragma unroll
    for (int k = 0; k < 2; k++)
        ap[k] = *(const short8*)(P + (r0 + l15) * PSTRIDE + quad * 8 + 32 * k);
    #pragma unroll
    for (int jt = 0; jt < 4; jt++) {
        short8 bv0 = *(const short8*)(Vt + (jt * 16 + l15) * PSTRIDE + quad * 8);
        short8 bv1 = *(const short8*)(Vt + (jt * 16 + l15) * PSTRIDE + quad * 8 + 32);
        f32x4 o = {};
        o = __builtin_amdgcn_mfma_f32_16x16x32_bf16(ap[0], bv0, o, 0, 0, 0);
        o = __builtin_amdgcn_mfma_f32_16x16x32_bf16(ap[1], bv1, o, 0, 0, 0);
        #pragma unroll
        for (int reg = 0; reg < 4; reg++) {
            int r = r0 + quad * 4 + reg;
            int c = jt * 16 + l15;
            O[(size_t)(b * SEQ + r) * D_MODEL + h * DHEAD + c] = __float2bfloat16(o[reg]);
        }
    }
}

// ---------------- loss: grid-stride waves, one atomic per wave ----------------
__global__ void zero_kernel(float* p) { if (threadIdx.x == 0) *p = 0.f; }

__global__ __launch_bounds__(256) void loss_kernel(
        const float* __restrict__ lg, const int* __restrict__ tgt,
        float* __restrict__ loss) {
    int wave = threadIdx.x >> 6;
    int l = threadIdx.x & 63;
    float local = 0.f;
    for (int row = blockIdx.x * 4 + wave; row < NTOK; row += gridDim.x * 4) {
        const float* lr = lg + (size_t)row * VOCAB;
        float a = lr[l];
        float bx = (l < VOCAB - 64) ? lr[64 + l] : -INFINITY;
        float m = fmaxf(a, bx);
        #pragma unroll
        for (int o = 32; o >= 1; o >>= 1) m = fmaxf(m, __shfl_xor(m, o));
        float s = expf(a - m) + ((l < VOCAB - 64) ? expf(bx - m) : 0.f);
        #pragma unroll
        for (int o = 32; o >= 1; o >>= 1) s += __shfl_xor(s, o);
        if (l == 0) local += lr[tgt[row]] - m - logf(s);
    }
    if (l == 0) atomicAdd(loss, -local / (float)NTOK);
}

extern "C" void kernel_launch(void* const* d_in, const int* in_sizes, int n_in,
                              void* d_out, int out_size, void* d_ws, size_t ws_size,
                              hipStream_t stream) {
    const int*   input_ids = (const int*)  d_in[0];
    const int*   targets   = (const int*)  d_in[1];
    const float* tok_emb   = (const float*)d_in[2];
    const float* pos_emb   = (const float*)d_in[3];
    const float* Wq        = (const float*)d_in[4];
    const float* Wk        = (const float*)d_in[5];
    const float* Wv        = (const float*)d_in[6];
    const float* Wo        = (const float*)d_in[7];
    const float* bo        = (const float*)d_in[8];
    const float* W1        = (const float*)d_in[9];
    const float* b1        = (const float*)d_in[10];
    const float* W2        = (const float*)d_in[11];
    const float* b2        = (const float*)d_in[12];
    const float* ln1_g     = (const float*)d_in[13];
    const float* ln1_b     = (const float*)d_in[14];
    const float* ln2_g     = (const float*)d_in[15];
    const float* ln2_b     = (const float*)d_in[16];
    const float* lnf_g     = (const float*)d_in[17];
    const float* lnf_b     = (const float*)d_in[18];
    const float* Wu        = (const float*)d_in[19];
    const float* bu        = (const float*)d_in[20];

    float* out  = (float*)d_out;
    float* loss = out + (size_t)NTOK * VOCAB;

    const size_t ND = (size_t)NTOK * D_MODEL;
    float* x             = (float*)d_ws;                         // [N,D] fp32 residual
    __hip_bfloat16* h    = (__hip_bfloat16*)(x + ND);            // [N,D] bf16 LN out
    __hip_bfloat16* qkv  = h + ND;                               // [N,1536] bf16
    __hip_bfloat16* ob   = qkv + 3 * ND;                         // [N,D] bf16
    __hip_bfloat16* hid  = qkv;                                  // [N,4D] bf16 (aliases)
    __hip_bfloat16* wqkvT = ob + ND;                             // [L][1536][512]
    __hip_bfloat16* woT   = wqkvT + (size_t)NLAYER * 1536 * 512; // [L][512][512]
    __hip_bfloat16* w1T   = woT + (size_t)NLAYER * 512 * 512;    // [L][2048][512]
    __hip_bfloat16* w2T   = w1T + (size_t)NLAYER * 2048 * 512;   // [L][512][2048]
    __hip_bfloat16* wuT   = w2T + (size_t)NLAYER * 2048 * 512;   // [128][512]

    // ---- weight convert + transpose ----
    transpose_conv<<<dim3(16, 16, NLAYER), 256, 0, stream>>>(Wq, wqkvT, 512, 512,
        (size_t)512 * 512, (size_t)1536 * 512, 0);
    transpose_conv<<<dim3(16, 16, NLAYER), 256, 0, stream>>>(Wk, wqkvT, 512, 512,
        (size_t)512 * 512, (size_t)1536 * 512, 512);
    transpose_conv<<<dim3(16, 16, NLAYER), 256, 0, stream>>>(Wv, wqkvT, 512, 512,
        (size_t)512 * 512, (size_t)1536 * 512, 1024);
    transpose_conv<<<dim3(16, 16, NLAYER), 256, 0, stream>>>(Wo, woT, 512, 512,
        (size_t)512 * 512, (size_t)512 * 512, 0);
    transpose_conv<<<dim3(64, 16, NLAYER), 256, 0, stream>>>(W1, w1T, 512, 2048,
        (size_t)512 * 2048, (size_t)2048 * 512, 0);
    transpose_conv<<<dim3(16, 64, NLAYER), 256, 0, stream>>>(W2, w2T, 2048, 512,
        (size_t)2048 * 512, (size_t)512 * 2048, 0);
    conv_wu<<<(128 * 512) / 256, 256, 0, stream>>>(Wu, wuT);

    embed_kernel<<<(NTOK * D_MODEL) / 256, 256, 0, stream>>>(input_ids, tok_emb, pos_emb, x);

    for (int l = 0; l < NLAYER; l++) {
        ln_kernel<<<NTOK / 4, 256, 0, stream>>>(x, ln1_g + l * D_MODEL, ln1_b + l * D_MODEL, h);
        mfma_gemm<0, 0><<<dim3(12, 128), 256, 0, stream>>>(
            h, wqkvT + (size_t)l * 1536 * 512, nullptr, nullptr, qkv, 512, 1536, 1536, 1536);
        attn_mfma<<<BATCH * NHEAD, 256, 0, stream>>>(qkv, ob);
        mfma_gemm<0, 1><<<dim3(4, 128), 256, 0, stream>>>(
            ob, woT + (size_t)l * 512 * 512, bo + l * D_MODEL, x, x, 512, 512, 512, 512);
        ln_kernel<<<NTOK / 4, 256, 0, stream>>>(x, ln2_g + l * D_MODEL, ln2_b + l * D_MODEL, h);
        mfma_gemm<1, 0><<<dim3(16, 128), 256, 0, stream>>>(
            h, w1T + (size_t)l * 2048 * 512, b1 + l * FFDIM, nullptr, hid, 512, 2048, 2048, 2048);
        mfma_gemm<0, 1><<<dim3(4, 128), 256, 0, stream>>>(
            hid, w2T + (size_t)l * 2048 * 512, b2 + l * D_MODEL, x, x, 2048, 512, 512, 512);
    }

    ln_kernel<<<NTOK / 4, 256, 0, stream>>>(x, lnf_g, lnf_b, h);
    mfma_gemm<0, 2><<<dim3(1, 128), 256, 0, stream>>>(
        h, wuT, bu, nullptr, out, 512, 128, VOCAB, VOCAB);
    zero_kernel<<<1, 64, 0, stream>>>(loss);
    loss_kernel<<<128, 256, 0, stream>>>(out, targets, loss);
}

// Round 5
// 2114.815 us; speedup vs baseline: 7.8639x; 1.1327x over previous
//
#include <hip/hip_runtime.h>
#include <hip/hip_bf16.h>
#include <math.h>

#define D_MODEL 512
#define NHEAD   8
#define DHEAD   64
#define SEQ     64
#define BATCH   256
#define NLAYER  8
#define VOCAB   66
#define FFDIM   2048
#define NTOK    (BATCH * SEQ)   // 16384 rows

typedef __attribute__((ext_vector_type(8))) short short8;    // 8 bf16 = 4 VGPRs
typedef __attribute__((ext_vector_type(4))) float f32x4;
typedef __attribute__((ext_vector_type(16))) float f32x16;

__device__ inline void async_copy16(const void* g, void* l) {
    __builtin_amdgcn_global_load_lds(
        (const __attribute__((address_space(1))) void*)g,
        (__attribute__((address_space(3))) void*)l,
        16, 0, 0);
}

// ---------------- weight fp32 [K,M] -> bf16 [M,K] transpose ----------------
__global__ __launch_bounds__(256) void transpose_conv(
        const float* __restrict__ W, __hip_bfloat16* __restrict__ Wt,
        int K, int M, size_t inLS, size_t outLS, int rowOff) {
    __shared__ float tile[32][33];
    int m0 = blockIdx.x * 32, k0 = blockIdx.y * 32;
    const float* Wl = W + blockIdx.z * inLS;
    __hip_bfloat16* Wtl = Wt + blockIdx.z * outLS;
    int t = threadIdx.x;
    #pragma unroll
    for (int p = 0; p < 4; p++) {
        int idx = t + p * 256;
        int kr = idx >> 5, mc = idx & 31;
        tile[kr][mc] = Wl[(size_t)(k0 + kr) * M + m0 + mc];
    }
    __syncthreads();
    #pragma unroll
    for (int p = 0; p < 4; p++) {
        int idx = t + p * 256;
        int mr = idx >> 5, kc = idx & 31;
        Wtl[(size_t)(rowOff + m0 + mr) * K + k0 + kc] = __float2bfloat16(tile[kc][mr]);
    }
}

// ---------------- Wu fp32 [512,66] -> bf16 [128,512] transposed, zero-padded ----
__global__ __launch_bounds__(256) void conv_wu(
        const float* __restrict__ Wu, __hip_bfloat16* __restrict__ WuT) {
    int idx = blockIdx.x * 256 + threadIdx.x;   // over 128*512
    int m = idx >> 9, k = idx & 511;
    WuT[idx] = __float2bfloat16(m < VOCAB ? Wu[(size_t)k * VOCAB + m] : 0.f);
}

// ---------------- embedding (fp32 residual) ----------------
__global__ void embed_kernel(const int* __restrict__ ids, const float* __restrict__ tok,
                             const float* __restrict__ pos, float* __restrict__ x) {
    int idx = blockIdx.x * 256 + threadIdx.x;
    int n = idx >> 9;
    int d = idx & 511;
    int s = n & (SEQ - 1);
    x[idx] = tok[ids[n] * D_MODEL + d] + pos[s * D_MODEL + d];
}

// ---------------- layernorm: wave per row, no barriers ----------------
__global__ __launch_bounds__(256) void ln_kernel(
        const float* __restrict__ x, const float* __restrict__ g,
        const float* __restrict__ b, __hip_bfloat16* __restrict__ y) {
    int row = blockIdx.x * 4 + (threadIdx.x >> 6);
    int lane = threadIdx.x & 63;
    const float* xr = x + (size_t)row * D_MODEL + lane * 8;
    f32x4 v0 = *(const f32x4*)xr;
    f32x4 v1 = *(const f32x4*)(xr + 4);
    float s = 0.f, ss = 0.f;
    #pragma unroll
    for (int e = 0; e < 4; e++) { s += v0[e] + v1[e]; ss += v0[e] * v0[e] + v1[e] * v1[e]; }
    #pragma unroll
    for (int o = 1; o < 64; o <<= 1) {
        s  += __shfl_xor(s, o);
        ss += __shfl_xor(ss, o);
    }
    float mean = s / (float)D_MODEL;
    float var = (ss - (float)D_MODEL * mean * mean) / (float)(D_MODEL - 1);
    float denom = sqrtf(fmaxf(var, 0.f)) + 1e-10f;
    f32x4 g0 = *(const f32x4*)(g + lane * 8);
    f32x4 g1 = *(const f32x4*)(g + lane * 8 + 4);
    f32x4 b0 = *(const f32x4*)(b + lane * 8);
    f32x4 b1 = *(const f32x4*)(b + lane * 8 + 4);
    short8 outv;
    #pragma unroll
    for (int e = 0; e < 4; e++) {
        outv[e]     = ((__hip_bfloat16_raw)__float2bfloat16((v0[e] - mean) / denom * g0[e] + b0[e])).x;
        outv[e + 4] = ((__hip_bfloat16_raw)__float2bfloat16((v1[e] - mean) / denom * g1[e] + b1[e])).x;
    }
    *(short8*)((short*)y + (size_t)row * D_MODEL + lane * 8) = outv;
}

// ---------------- bf16 MFMA GEMM (32x32x16, BK=64, XOR-swizzled LDS) ----------------
// A [N,K] bf16 row-major; Bt [M,K] bf16 row-major (pre-transposed weight).
// Tile 128x128, BK=64, 4 waves 2x2, each wave 64x64 = 2x2 of 32x32 tiles.
// LDS: 16B chunk (row, kg) stored at chunk index row*8 + (kg ^ (row&7)).
// Staging applies the inverse permutation on the *global* source address, so
// global_load_lds dests remain wave-uniform-base + lane*16.
// OUTMODE 0: bf16 store. 1: fp32 store + addsrc residual.
// 2: fp32 store, ldc row stride, col < mstore guard (logits).
template <int ACT, int OUTMODE>
__global__ __launch_bounds__(256) void mfma_gemm(
        const __hip_bfloat16* __restrict__ A, const __hip_bfloat16* __restrict__ Bt,
        const float* __restrict__ bias, const float* addsrc,
        void* Cout, int K, int M, int ldc, int mstore) {
    __shared__ __align__(16) short As[128 * 64];   // 16 KB
    __shared__ __align__(16) short Bs[128 * 64];   // 16 KB
    int tid = threadIdx.x;
    int lane = tid & 63, wave = tid >> 6;
    int row0 = blockIdx.y * 128, col0 = blockIdx.x * 128;
    int wr = (wave >> 1) * 64, wc = (wave & 1) * 64;
    int l31 = lane & 31, h32 = lane >> 5;
    int l7 = l31 & 7;

    f32x16 acc[2][2] = {};

    // staging source offsets (swizzled) for the 4 copy instructions
    int srow[4], skg[4];
    #pragma unroll
    for (int s = 0; s < 4; s++) {
        int u = s * 256 + tid;
        srow[s] = u >> 3;
        skg[s] = (u & 7) ^ (srow[s] & 7);
    }

    for (int k0 = 0; k0 < K; k0 += 64) {
        #pragma unroll
        for (int s = 0; s < 4; s++) {
            int u = s * 256 + tid;
            async_copy16((const short*)A + (size_t)(row0 + srow[s]) * K + k0 + skg[s] * 8,
                         As + u * 8);
            async_copy16((const short*)Bt + (size_t)(col0 + srow[s]) * K + k0 + skg[s] * 8,
                         Bs + u * 8);
        }
        __syncthreads();
        short8 af[2][4], bf[2][4];
        #pragma unroll
        for (int i = 0; i < 2; i++)
            #pragma unroll
            for (int kk = 0; kk < 4; kk++) {
                int kg = kk * 2 + h32;
                int c = kg ^ l7;
                af[i][kk] = *(const short8*)(As + ((wr + i * 32 + l31) * 8 + c) * 8);
                bf[i][kk] = *(const short8*)(Bs + ((wc + i * 32 + l31) * 8 + c) * 8);
            }
        #pragma unroll
        for (int i = 0; i < 2; i++)
            #pragma unroll
            for (int j = 0; j < 2; j++)
                #pragma unroll
                for (int kk = 0; kk < 4; kk++)
                    acc[i][j] = __builtin_amdgcn_mfma_f32_32x32x16_bf16(
                        af[i][kk], bf[j][kk], acc[i][j], 0, 0, 0);
        __syncthreads();
    }

    // C/D layout: col = lane&31, row = (reg&3) + 8*(reg>>2) + 4*(lane>>5)
    #pragma unroll
    for (int j = 0; j < 2; j++) {
        int col = col0 + wc + j * 32 + l31;
        if (OUTMODE == 2 && col >= mstore) continue;
        float bv = bias ? bias[col] : 0.f;
        #pragma unroll
        for (int i = 0; i < 2; i++) {
            int rbase = row0 + wr + i * 32 + 4 * h32;
            #pragma unroll
            for (int r = 0; r < 16; r++) {
                int row = rbase + (r & 3) + 8 * (r >> 2);
                float v = acc[i][j][r] + bv;
                if (OUTMODE == 1) v += addsrc[(size_t)row * M + col];
                if (ACT == 1) v = 0.5f * v * (1.f + erff(v * 0.70710678118654752f));
                if (OUTMODE == 0)
                    ((__hip_bfloat16*)Cout)[(size_t)row * M + col] = __float2bfloat16(v);
                else
                    ((float*)Cout)[(size_t)row * ldc + col] = v;
            }
        }
    }
}

// ---------------- MFMA causal attention: one block per (b,h) ----------------
#define PSTRIDE 72
__global__ __launch_bounds__(256) void attn_mfma(
        const __hip_bfloat16* __restrict__ QKV, __hip_bfloat16* __restrict__ O) {
    __shared__ __align__(16) short Vt[64 * PSTRIDE];   // Vt[c][j] = V[j][c]
    __shared__ __align__(16) short P[64 * PSTRIDE];    // P[r][j]
    int bh = blockIdx.x;
    int b = bh >> 3, h = bh & 7;
    int t = threadIdx.x;
    int lane = t & 63, wave = t >> 6;
    int l15 = lane & 15, quad = lane >> 4;
    const float scale = 0.04419417382415922f;  // 1/sqrt(512)
    const short* base = (const short*)QKV + (size_t)(b * SEQ) * 1536 + h * DHEAD;

    // cooperative V transpose into LDS
    {
        int j0 = (t >> 3) * 2;
        int c0 = (t & 7) * 8;
        const short* vrow = base + 1024 + (size_t)j0 * 1536 + c0;
        short8 va = *(const short8*)vrow;
        short8 vb = *(const short8*)(vrow + 1536);
        #pragma unroll
        for (int s = 0; s < 8; s++) {
            unsigned int packed = ((unsigned int)(unsigned short)vb[s] << 16) |
                                  (unsigned int)(unsigned short)va[s];
            *(unsigned int*)&Vt[(c0 + s) * PSTRIDE + j0] = packed;
        }
    }

    // QK^T for this wave's 16 rows
    int r0 = wave * 16;
    short8 aq[2], bk[4][2];
    #pragma unroll
    for (int k = 0; k < 2; k++)
        aq[k] = *(const short8*)(base + (size_t)(r0 + l15) * 1536 + quad * 8 + 32 * k);
    #pragma unroll
    for (int j = 0; j < 4; j++)
        #pragma unroll
        for (int k = 0; k < 2; k++)
            bk[j][k] = *(const short8*)(base + 512 + (size_t)(j * 16 + l15) * 1536 + quad * 8 + 32 * k);

    f32x4 sc[4];
    #pragma unroll
    for (int j = 0; j < 4; j++) {
        f32x4 z = {};
        z = __builtin_amdgcn_mfma_f32_16x16x32_bf16(aq[0], bk[j][0], z, 0, 0, 0);
        sc[j] = __builtin_amdgcn_mfma_f32_16x16x32_bf16(aq[1], bk[j][1], z, 0, 0, 0);
    }

    // softmax per row
    float p[4][4];
    #pragma unroll
    for (int reg = 0; reg < 4; reg++) {
        int r = r0 + quad * 4 + reg;
        float m = -INFINITY;
        #pragma unroll
        for (int j = 0; j < 4; j++) {
            int c = j * 16 + l15;
            float s = (c <= r) ? sc[j][reg] * scale : -INFINITY;
            p[j][reg] = s;
            m = fmaxf(m, s);
        }
        #pragma unroll
        for (int o = 1; o < 16; o <<= 1) m = fmaxf(m, __shfl_xor(m, o));
        float sum = 0.f;
        #pragma unroll
        for (int j = 0; j < 4; j++) {
            float e = (p[j][reg] == -INFINITY) ? 0.f : expf(p[j][reg] - m);
            p[j][reg] = e;
            sum += e;
        }
        #pragma unroll
        for (int o = 1; o < 16; o <<= 1) sum += __shfl_xor(sum, o);
        float inv = 1.f / sum;
        #pragma unroll
        for (int j = 0; j < 4; j++) p[j][reg] *= inv;
    }

    // write P (bf16) to LDS
    #pragma unroll
    for (int j = 0; j < 4; j++)
        #pragma unroll
        for (int reg = 0; reg < 4; reg++) {
            int r = r0 + quad * 4 + reg;
            P[r * PSTRIDE + j * 16 + l15] =
                ((__hip_bfloat16_raw)__float2bfloat16(p[j][reg])).x;
        }

    __syncthreads();

    // PV
    short8 ap[2];
    #pragma unroll
    for (int k = 0; k < 2; k++)
        ap[k] = *(const short8*)(P + (r0 + l15) * PSTRIDE + quad * 8 + 32 * k);
    #pragma unroll
    for (int jt = 0; jt < 4; jt++) {
        short8 bv0 = *(const short8*)(Vt + (jt * 16 + l15) * PSTRIDE + quad * 8);
        short8 bv1 = *(const short8*)(Vt + (jt * 16 + l15) * PSTRIDE + quad * 8 + 32);
        f32x4 o = {};
        o = __builtin_amdgcn_mfma_f32_16x16x32_bf16(ap[0], bv0, o, 0, 0, 0);
        o = __builtin_amdgcn_mfma_f32_16x16x32_bf16(ap[1], bv1, o, 0, 0, 0);
        #pragma unroll
        for (int reg = 0; reg < 4; reg++) {
            int r = r0 + quad * 4 + reg;
            int c = jt * 16 + l15;
            O[(size_t)(b * SEQ + r) * D_MODEL + h * DHEAD + c] = __float2bfloat16(o[reg]);
        }
    }
}

// ---------------- loss: grid-stride waves, one atomic per wave ----------------
__global__ void zero_kernel(float* p) { if (threadIdx.x == 0) *p = 0.f; }

__global__ __launch_bounds__(256) void loss_kernel(
        const float* __restrict__ lg, const int* __restrict__ tgt,
        float* __restrict__ loss) {
    int wave = threadIdx.x >> 6;
    int l = threadIdx.x & 63;
    float local = 0.f;
    for (int row = blockIdx.x * 4 + wave; row < NTOK; row += gridDim.x * 4) {
        const float* lr = lg + (size_t)row * VOCAB;
        float a = lr[l];
        float bx = (l < VOCAB - 64) ? lr[64 + l] : -INFINITY;
        float m = fmaxf(a, bx);
        #pragma unroll
        for (int o = 32; o >= 1; o >>= 1) m = fmaxf(m, __shfl_xor(m, o));
        float s = expf(a - m) + ((l < VOCAB - 64) ? expf(bx - m) : 0.f);
        #pragma unroll
        for (int o = 32; o >= 1; o >>= 1) s += __shfl_xor(s, o);
        if (l == 0) local += lr[tgt[row]] - m - logf(s);
    }
    if (l == 0) atomicAdd(loss, -local / (float)NTOK);
}

extern "C" void kernel_launch(void* const* d_in, const int* in_sizes, int n_in,
                              void* d_out, int out_size, void* d_ws, size_t ws_size,
                              hipStream_t stream) {
    const int*   input_ids = (const int*)  d_in[0];
    const int*   targets   = (const int*)  d_in[1];
    const float* tok_emb   = (const float*)d_in[2];
    const float* pos_emb   = (const float*)d_in[3];
    const float* Wq        = (const float*)d_in[4];
    const float* Wk        = (const float*)d_in[5];
    const float* Wv        = (const float*)d_in[6];
    const float* Wo        = (const float*)d_in[7];
    const float* bo        = (const float*)d_in[8];
    const float* W1        = (const float*)d_in[9];
    const float* b1        = (const float*)d_in[10];
    const float* W2        = (const float*)d_in[11];
    const float* b2        = (const float*)d_in[12];
    const float* ln1_g     = (const float*)d_in[13];
    const float* ln1_b     = (const float*)d_in[14];
    const float* ln2_g     = (const float*)d_in[15];
    const float* ln2_b     = (const float*)d_in[16];
    const float* lnf_g     = (const float*)d_in[17];
    const float* lnf_b     = (const float*)d_in[18];
    const float* Wu        = (const float*)d_in[19];
    const float* bu        = (const float*)d_in[20];

    float* out  = (float*)d_out;
    float* loss = out + (size_t)NTOK * VOCAB;

    const size_t ND = (size_t)NTOK * D_MODEL;
    float* x             = (float*)d_ws;                         // [N,D] fp32 residual
    __hip_bfloat16* h    = (__hip_bfloat16*)(x + ND);            // [N,D] bf16 LN out
    __hip_bfloat16* qkv  = h + ND;                               // [N,1536] bf16
    __hip_bfloat16* ob   = qkv + 3 * ND;                         // [N,D] bf16
    __hip_bfloat16* hid  = qkv;                                  // [N,4D] bf16 (aliases)
    __hip_bfloat16* wqkvT = ob + ND;                             // [L][1536][512]
    __hip_bfloat16* woT   = wqkvT + (size_t)NLAYER * 1536 * 512; // [L][512][512]
    __hip_bfloat16* w1T   = woT + (size_t)NLAYER * 512 * 512;    // [L][2048][512]
    __hip_bfloat16* w2T   = w1T + (size_t)NLAYER * 2048 * 512;   // [L][512][2048]
    __hip_bfloat16* wuT   = w2T + (size_t)NLAYER * 2048 * 512;   // [128][512]

    // ---- weight convert + transpose ----
    transpose_conv<<<dim3(16, 16, NLAYER), 256, 0, stream>>>(Wq, wqkvT, 512, 512,
        (size_t)512 * 512, (size_t)1536 * 512, 0);
    transpose_conv<<<dim3(16, 16, NLAYER), 256, 0, stream>>>(Wk, wqkvT, 512, 512,
        (size_t)512 * 512, (size_t)1536 * 512, 512);
    transpose_conv<<<dim3(16, 16, NLAYER), 256, 0, stream>>>(Wv, wqkvT, 512, 512,
        (size_t)512 * 512, (size_t)1536 * 512, 1024);
    transpose_conv<<<dim3(16, 16, NLAYER), 256, 0, stream>>>(Wo, woT, 512, 512,
        (size_t)512 * 512, (size_t)512 * 512, 0);
    transpose_conv<<<dim3(64, 16, NLAYER), 256, 0, stream>>>(W1, w1T, 512, 2048,
        (size_t)512 * 2048, (size_t)2048 * 512, 0);
    transpose_conv<<<dim3(16, 64, NLAYER), 256, 0, stream>>>(W2, w2T, 2048, 512,
        (size_t)2048 * 512, (size_t)512 * 2048, 0);
    conv_wu<<<(128 * 512) / 256, 256, 0, stream>>>(Wu, wuT);

    embed_kernel<<<(NTOK * D_MODEL) / 256, 256, 0, stream>>>(input_ids, tok_emb, pos_emb, x);

    for (int l = 0; l < NLAYER; l++) {
        ln_kernel<<<NTOK / 4, 256, 0, stream>>>(x, ln1_g + l * D_MODEL, ln1_b + l * D_MODEL, h);
        mfma_gemm<0, 0><<<dim3(12, 128), 256, 0, stream>>>(
            h, wqkvT + (size_t)l * 1536 * 512, nullptr, nullptr, qkv, 512, 1536, 1536, 1536);
        attn_mfma<<<BATCH * NHEAD, 256, 0, stream>>>(qkv, ob);
        mfma_gemm<0, 1><<<dim3(4, 128), 256, 0, stream>>>(
            ob, woT + (size_t)l * 512 * 512, bo + l * D_MODEL, x, x, 512, 512, 512, 512);
        ln_kernel<<<NTOK / 4, 256, 0, stream>>>(x, ln2_g + l * D_MODEL, ln2_b + l * D_MODEL, h);
        mfma_gemm<1, 0><<<dim3(16, 128), 256, 0, stream>>>(
            h, w1T + (size_t)l * 2048 * 512, b1 + l * FFDIM, nullptr, hid, 512, 2048, 2048, 2048);
        mfma_gemm<0, 1><<<dim3(4, 128), 256, 0, stream>>>(
            hid, w2T + (size_t)l * 2048 * 512, b2 + l * D_MODEL, x, x, 2048, 512, 512, 512);
    }

    ln_kernel<<<NTOK / 4, 256, 0, stream>>>(x, lnf_g, lnf_b, h);
    mfma_gemm<0, 2><<<dim3(1, 128), 256, 0, stream>>>(
        h, wuT, bu, nullptr, out, 512, 128, VOCAB, VOCAB);
    zero_kernel<<<1, 64, 0, stream>>>(loss);
    loss_kernel<<<128, 256, 0, stream>>>(out, targets, loss);
}